// Round 11
// baseline (404.297 us; speedup 1.0000x reference)
//
#include <hip/hip_runtime.h>
#include <math.h>

constexpr int TT = 12;
constexpr int NN = 325;
constexpr int MM = 975;   // 3*NN
constexpr int DD = 64;
constexpr long SZ = 96L * MM * DD;       // 5,990,400 elements per big tensor
constexpr int GSTR = 352;                // gso row stride (fp16 shorts), zero-padded
constexpr int MBSTR = 48;                // mask bitrow stride (bytes), 384 bits
constexpr int VTS = 22528;               // vbT per-seg elements (64*352)
constexpr float BN_EPS_ = 1e-5f;
constexpr float LN_EPS_ = 1e-5f;

// ---- workspace float offsets (running map) -------------------------------
constexpr long WS_MASKB = 0;                          // 15,600 B -> 4,096 f
constexpr long WS_GSOB  = WS_MASKB + 4096;            // 457,600 f
constexpr long WS_STXB  = WS_GSOB + 457600;           // SZ/2 f
constexpr long WS_QB    = WS_STXB + SZ / 2;
constexpr long WS_KB    = WS_QB + SZ / 2;
constexpr long WS_VB    = WS_KB + SZ / 2;
constexpr long WS_VT    = WS_VB + SZ / 2;             // 3,244,032 f
constexpr long WS_SEMH  = WS_VT + 3244032;            // SZ/2 f
constexpr long WS_T2B   = WS_SEMH + SZ / 2;           // 998,400 f
constexpr long WS_MBD   = WS_T2B + 998400;            // mbd 512 + xg 512

typedef _Float16 half8 __attribute__((ext_vector_type(8)));
typedef __attribute__((ext_vector_type(4))) float f32x4;

static __device__ inline unsigned short f2h(float f) {
  _Float16 h = (_Float16)f;
  return __builtin_bit_cast(unsigned short, h);
}
static __device__ inline float h2f(unsigned short s) {
  return (float)__builtin_bit_cast(_Float16, s);
}

// ------------- mask sniff + pack to bitmask [NN][MBSTR] -------------------
__global__ __launch_bounds__(256) void k_maskprep(const unsigned char* __restrict__ raw,
                                                  unsigned char* __restrict__ outm) {
  bool is_u8 = false;
  for (int i = 0; i < 256; ++i) {
    if (raw[4 * i + 1]) { is_u8 = true; break; }
  }
  int idx = blockIdx.x * 256 + threadIdx.x;     // NN*MBSTR = 15,600 bytes
  if (idx >= NN * MBSTR) return;
  int n = idx / MBSTR, jb = idx - n * MBSTR;
  unsigned char v = 0;
  for (int k = 0; k < 8; ++k) {
    int col = jb * 8 + k;
    bool m = true;                               // pad cols -> masked
    if (col < NN) {
      int f = n * NN + col;
      m = is_u8 ? (raw[f] != 0) : (((const int*)raw)[f] != 0);
    }
    v |= (unsigned char)(m ? 1 : 0) << k;
  }
  outm[idx] = v;
}

// ------------- gso -> fp16, padded rows [8][325][GSTR] --------------------
__global__ __launch_bounds__(256) void k_gsoprep(const float* __restrict__ gso,
                                                 unsigned short* __restrict__ gsoB) {
  int idx = blockIdx.x * 256 + threadIdx.x;   // 3575 blocks exact
  int b = idx / (NN * GSTR);
  int rem = idx - b * (NN * GSTR);
  int r = rem / GSTR, j = rem - r * GSTR;
  gsoB[idx] = (j < NN) ? f2h(gso[(long)b * NN * NN + r * NN + j]) : (unsigned short)0;
}

// ---------------- stX gather: [B,T,N,D] -> [BT, 3N, D] fp16 ---------------
__global__ __launch_bounds__(256) void k_stx(const float* __restrict__ x,
                                             unsigned short* __restrict__ stXb) {
  int idx = blockIdx.x * 256 + threadIdx.x;     // exact: 23,400 blocks
  int d = idx & 63;
  int m = (idx >> 6) % MM;
  int bt = idx / (MM * DD);
  int b = bt / TT, t = bt - b * TT;
  int w = m / NN, n = m - w * NN;
  int st = t + w - 1;
  st = st < 0 ? 0 : (st > TT - 1 ? TT - 1 : st);
  stXb[idx] = f2h(x[(((b * TT + st) * NN + n) << 6) + d]);
}

// ---------------- QKV via MFMA: [93600x64] x [64x64] -> fp16 -------------
__global__ __launch_bounds__(256) void k_qkv_mfma(const unsigned short* __restrict__ stXb,
                                                  const float* __restrict__ Wq,
                                                  const float* __restrict__ Wk,
                                                  const float* __restrict__ Wv,
                                                  unsigned short* __restrict__ qb,
                                                  unsigned short* __restrict__ kb,
                                                  unsigned short* __restrict__ vb) {
  __shared__ alignas(16) unsigned short sX[128 * 72];
  __shared__ alignas(16) unsigned short sW[64 * 72];
  const float* W = blockIdx.y == 0 ? Wq : (blockIdx.y == 1 ? Wk : Wv);
  unsigned short* outb = blockIdx.y == 0 ? qb : (blockIdx.y == 1 ? kb : vb);
  int tid = threadIdx.x;
  long r0 = (long)blockIdx.x * 128;
  for (int u = 0; u < 4; ++u) {
    int idx = tid + 256 * u;
    int row = idx >> 3, c8 = idx & 7;
    long rg = r0 + row; if (rg > 93599) rg = 93599;
    *(uint4*)&sX[row * 72 + c8 * 8] = *(const uint4*)&stXb[rg * 64 + c8 * 8];
  }
  for (int u = 0; u < 16; ++u) {
    int f = tid + 256 * u;
    int o = f >> 6, d = f & 63;
    sW[o * 72 + d] = f2h(W[f]);
  }
  __syncthreads();
  int lane = tid & 63;
  int wv = __builtin_amdgcn_readfirstlane(tid >> 6);
  int lr = lane & 15, lg = lane >> 4;
  f32x4 zero4 = {0.f, 0.f, 0.f, 0.f};
  f32x4 acc[2][4];
#pragma unroll
  for (int rt = 0; rt < 2; ++rt)
#pragma unroll
    for (int c = 0; c < 4; ++c) acc[rt][c] = zero4;
#pragma unroll
  for (int kk = 0; kk < 2; ++kk) {
    half8 a0 = *(const half8*)&sX[(32 * wv + lr) * 72 + kk * 32 + lg * 8];
    half8 a1 = *(const half8*)&sX[(32 * wv + 16 + lr) * 72 + kk * 32 + lg * 8];
#pragma unroll
    for (int c = 0; c < 4; ++c) {
      half8 b = *(const half8*)&sW[(16 * c + lr) * 72 + kk * 32 + lg * 8];
      acc[0][c] = __builtin_amdgcn_mfma_f32_16x16x32_f16(a0, b, acc[0][c], 0, 0, 0);
      acc[1][c] = __builtin_amdgcn_mfma_f32_16x16x32_f16(a1, b, acc[1][c], 0, 0, 0);
    }
  }
  __syncthreads();
#pragma unroll
  for (int rt = 0; rt < 2; ++rt)
#pragma unroll
    for (int c = 0; c < 4; ++c)
#pragma unroll
      for (int e = 0; e < 4; ++e) {
        int row = 32 * wv + 16 * rt + lg * 4 + e;
        int col = 16 * c + lr;
        sX[row * 64 + col] = f2h(acc[rt][c][e]);
      }
  __syncthreads();
  for (int u = 0; u < 4; ++u) {
    int idx = tid + 256 * u;
    int row = idx >> 3, c8 = idx & 7;
    long rg = r0 + row;
    if (rg < 93600)
      *(uint4*)&outb[rg * 64 + c8 * 8] = *(const uint4*)&sX[row * 64 + c8 * 8];
  }
}

// ------- V transpose: vb [seg*NN+k][64] -> vbT [seg][64][352] ------------
__global__ __launch_bounds__(256) void k_vT(const unsigned short* __restrict__ vb,
                                            unsigned short* __restrict__ vbT) {
  __shared__ alignas(16) unsigned short T[128 * 72];
  int seg = blockIdx.x;                  // 0..287
  int ck = blockIdx.y;                   // 0..2 (k chunks of 128)
  int tid = threadIdx.x;
  long base = (long)seg * NN * 64;
  int k0 = ck * 128;
  for (int u = 0; u < 4; ++u) {
    int idx = tid + 256 * u;
    int row = idx >> 3, c8 = idx & 7;
    int kg = k0 + row;
    uint4 v;
    if (kg < NN) v = *(const uint4*)&vb[base + (long)kg * 64 + c8 * 8];
    else { v.x = 0; v.y = 0; v.z = 0; v.w = 0; }
    *(uint4*)&T[row * 72 + c8 * 8] = v;
  }
  __syncthreads();
  int d = tid & 63, k8 = tid >> 6;
  for (int it = 0; it < 4; ++it) {
    int klocal = (it * 4 + k8) * 8;
    if (k0 + klocal < 352) {
      unsigned short tmp[8];
#pragma unroll
      for (int j = 0; j < 8; ++j) tmp[j] = T[(klocal + j) * 72 + d];
      *(uint4*)&vbT[(long)seg * VTS + (long)d * 352 + k0 + klocal] = *(const uint4*)tmp;
    }
  }
}

// ------- fused attention: 4 INDEPENDENT waves per block (no barriers) ----
// wave gid = bswz*4+wv in [0,6048): seg = gid/21, rti = gid%21 (16 rows).
// Block-level XCD swizzle keeps a seg's tiles on one XCD's L2.
__global__ __launch_bounds__(256) void k_attn(const unsigned short* __restrict__ qb,
                                              const unsigned short* __restrict__ kb,
                                              const unsigned short* __restrict__ vb,
                                              const unsigned short* __restrict__ vbT,
                                              const unsigned char* __restrict__ maskb,
                                              unsigned short* __restrict__ semh) {
  __shared__ alignas(16) unsigned short Ptr4[4 * 16 * 40];  // per-wave P scratch
  int bid = blockIdx.x;                       // 1512 = 8 * 189 exact
  int bswz = (bid & 7) * 189 + (bid >> 3);
  int wv = __builtin_amdgcn_readfirstlane((int)(threadIdx.x >> 6));
  int gid = bswz * 4 + wv;
  int seg = gid / 21, rti = gid - seg * 21;
  int bt = seg / 3, w = seg - bt * 3;
  int n0 = rti * 16;
  long segbase = (long)seg * NN * 64;
  int lane = threadIdx.x & 63;
  int lr = lane & 15, lg = lane >> 4;
  f32x4 zero4 = {0.f, 0.f, 0.f, 0.f};
  f32x4 acc[21];
#pragma unroll
  for (int ct = 0; ct < 21; ++ct) acc[ct] = zero4;
  f32x4 dA = zero4, dB = zero4;
  int arow = n0 + lr; if (arow > NN - 1) arow = NN - 1;
  long abase = segbase + (long)arow * 64;
  long pAaddr = ((long)bt * MM + ((w == 1) ? arow : NN + arow)) * 64;
  long pBaddr = ((long)bt * MM + 2 * NN + arow) * 64;
#pragma unroll
  for (int kk = 0; kk < 2; ++kk) {
    half8 a = *(const half8*)&qb[abase + kk * 32 + lg * 8];
#pragma unroll
    for (int ct = 0; ct < 21; ++ct) {
      int brow = 16 * ct + lr; if (brow > NN - 1) brow = NN - 1;
      half8 b = *(const half8*)&kb[segbase + (long)brow * 64 + kk * 32 + lg * 8];
      acc[ct] = __builtin_amdgcn_mfma_f32_16x16x32_f16(a, b, acc[ct], 0, 0, 0);
    }
    half8 bA = *(const half8*)&kb[pAaddr + kk * 32 + lg * 8];
    dA = __builtin_amdgcn_mfma_f32_16x16x32_f16(a, bA, dA, 0, 0, 0);
    if (w == 1) {
      half8 bB = *(const half8*)&kb[pBaddr + kk * 32 + lg * 8];
      dB = __builtin_amdgcn_mfma_f32_16x16x32_f16(a, bB, dB, 0, 0, 0);
    }
  }
  // diag extraction: element (r,r) at lane 20*lg+e for r = lg*4+e
  float da_[4], db_[4];
#pragma unroll
  for (int e = 0; e < 4; ++e) {
    int src = lg * 20 + e;
    da_[e] = __shfl(dA[e], src);
    db_[e] = (w == 1) ? __shfl(dB[e], src) : -INFINITY;
  }
  // mask (global dword bit tests; 16 lr-lanes share address -> broadcast)
  int rl[4];
#pragma unroll
  for (int e = 0; e < 4; ++e) {
    int r = n0 + lg * 4 + e; if (r > NN - 1) r = NN - 1;
    rl[e] = r;
  }
  float mx[4] = {-INFINITY, -INFINITY, -INFINITY, -INFINITY};
  unsigned mw[4];
#pragma unroll
  for (int ct = 0; ct < 21; ++ct) {
    if ((ct & 1) == 0) {
#pragma unroll
      for (int e = 0; e < 4; ++e)
        mw[e] = *(const unsigned*)&maskb[(long)rl[e] * MBSTR + (ct >> 1) * 4];
    }
    int sh = 16 * (ct & 1) + lr;
#pragma unroll
    for (int e = 0; e < 4; ++e) {
      bool masked = (mw[e] >> sh) & 1;
      float s = masked ? -INFINITY : acc[ct][e];
      acc[ct][e] = s;
      mx[e] = fmaxf(mx[e], s);
    }
  }
#pragma unroll
  for (int e = 0; e < 4; ++e)
    for (int m = 1; m < 16; m <<= 1) mx[e] = fmaxf(mx[e], __shfl_xor(mx[e], m));
  float gm[4], ea[4], eb[4], sum[4], inv[4];
#pragma unroll
  for (int e = 0; e < 4; ++e) {
    gm[e] = fmaxf(mx[e], da_[e]);
    if (w == 1) gm[e] = fmaxf(gm[e], db_[e]);
    sum[e] = 0.f;
  }
#pragma unroll
  for (int ct = 0; ct < 21; ++ct)
#pragma unroll
    for (int e = 0; e < 4; ++e) {
      float s = acc[ct][e];
      float p = (s > -1e37f) ? __expf(s - gm[e]) : 0.f;
      acc[ct][e] = p;
      sum[e] += p;
    }
#pragma unroll
  for (int e = 0; e < 4; ++e) {
    for (int m = 1; m < 16; m <<= 1) sum[e] += __shfl_xor(sum[e], m);
    ea[e] = __expf(da_[e] - gm[e]);
    eb[e] = (w == 1) ? __expf(db_[e] - gm[e]) : 0.f;
    sum[e] += ea[e] + eb[e];
    inv[e] = 1.f / sum[e];
  }
  // PV: per-wave P transpose scratch; B-frags from global vbT
  unsigned short* Ptr = Ptr4 + wv * 640;      // [16][40]
  long vtbase = (long)seg * VTS;
  f32x4 oacc[4];
#pragma unroll
  for (int c = 0; c < 4; ++c) oacc[c] = zero4;
#pragma unroll
  for (int ck = 0; ck < 11; ++ck) {
#pragma unroll
    for (int t = 0; t < 2; ++t) {
      int ct = 2 * ck + t;
#pragma unroll
      for (int e = 0; e < 4; ++e) {
        float pv = (ct < 21) ? acc[ct][e] * inv[e] : 0.f;
        Ptr[(lg * 4 + e) * 40 + t * 16 + lr] = f2h(pv);
      }
    }
    half8 a = *(const half8*)&Ptr[lr * 40 + lg * 8];
#pragma unroll
    for (int c = 0; c < 4; ++c) {
      half8 b = *(const half8*)&vbT[vtbase + (long)(16 * c + lr) * 352 + ck * 32 + lg * 8];
      oacc[c] = __builtin_amdgcn_mfma_f32_16x16x32_f16(a, b, oacc[c], 0, 0, 0);
    }
  }
  // epilogue: diag-partner contributions + write semh
#pragma unroll
  for (int c = 0; c < 4; ++c)
#pragma unroll
    for (int e = 0; e < 4; ++e) {
      int n = n0 + lg * 4 + e;
      int col = 16 * c + lr;
      if (n < NN) {
        float val = oacc[c][e];
        int partA = (w == 1) ? n : NN + n;
        val += ea[e] * inv[e] * h2f(vb[((long)bt * MM + partA) * 64 + col]);
        if (w == 1)
          val += eb[e] * inv[e] * h2f(vb[((long)bt * MM + 2 * NN + n) * 64 + col]);
        semh[((long)bt * MM + (long)w * NN + n) * 64 + col] = f2h(val);
      }
    }
}

// ---------------- xs1 via MFMA: gso x stX(block) + diag epilogue ---------
__global__ __launch_bounds__(256) void k_xs1_mfma(const unsigned short* __restrict__ gsoB,
                                                  const unsigned short* __restrict__ stXb,
                                                  const float* __restrict__ pt12,
                                                  const float* __restrict__ pt21,
                                                  const float* __restrict__ pt23,
                                                  const float* __restrict__ pt32,
                                                  unsigned short* __restrict__ xs1b) {
  __shared__ alignas(16) unsigned short Al[128 * 40];
  __shared__ alignas(16) unsigned short Bt[64 * 40];
  int btw = blockIdx.x;
  int bt = btw / 3, w = btw - bt * 3;
  int b = bt / TT;
  int rt_blk = blockIdx.y;
  const unsigned short* A = gsoB + (long)b * NN * GSTR;
  long vbase = (long)bt * MM + (long)w * NN;
  int tid = threadIdx.x;
  int lane = tid & 63;
  int wv = __builtin_amdgcn_readfirstlane(tid >> 6);
  int lr = lane & 15, lg = lane >> 4;
  f32x4 zero4 = {0.f, 0.f, 0.f, 0.f};
  f32x4 acc[2][4];
#pragma unroll
  for (int rt = 0; rt < 2; ++rt)
#pragma unroll
    for (int c = 0; c < 4; ++c) acc[rt][c] = zero4;
  for (int kb_ = 0; kb_ < 352; kb_ += 32) {
    __syncthreads();
    for (int u = 0; u < 2; ++u) {
      int idx = tid + 256 * u;
      int row = idx >> 2, c8 = idx & 3;
      int rr = rt_blk * 128 + row; if (rr > NN - 1) rr = NN - 1;
      *(uint4*)&Al[row * 40 + c8 * 8] = *(const uint4*)&A[(long)rr * GSTR + kb_ + c8 * 8];
    }
    for (int u = 0; u < 2; ++u) {
      int idx = tid + 256 * u;
      int k = idx >> 4, c4 = idx & 15;
      int kg = kb_ + k;
#pragma unroll
      for (int j = 0; j < 4; ++j) {
        int d = c4 + 16 * j;
        unsigned short val = (kg < NN) ? stXb[(vbase + kg) * 64 + d] : (unsigned short)0;
        Bt[d * 40 + k] = val;
      }
    }
    __syncthreads();
    half8 a0 = *(const half8*)&Al[(32 * wv + lr) * 40 + lg * 8];
    half8 a1 = *(const half8*)&Al[(32 * wv + 16 + lr) * 40 + lg * 8];
#pragma unroll
    for (int c = 0; c < 4; ++c) {
      half8 b_ = *(const half8*)&Bt[(16 * c + lr) * 40 + lg * 8];
      acc[0][c] = __builtin_amdgcn_mfma_f32_16x16x32_f16(a0, b_, acc[0][c], 0, 0, 0);
      acc[1][c] = __builtin_amdgcn_mfma_f32_16x16x32_f16(a1, b_, acc[1][c], 0, 0, 0);
    }
  }
  long btM = (long)bt * MM;
#pragma unroll
  for (int rt = 0; rt < 2; ++rt)
#pragma unroll
    for (int c = 0; c < 4; ++c)
#pragma unroll
      for (int e = 0; e < 4; ++e) {
        int n = rt_blk * 128 + 32 * wv + 16 * rt + lg * 4 + e;
        int col = 16 * c + lr;
        if (n < NN) {
          float val = acc[rt][c][e];
          if (w == 0) {
            val += pt21[n] * h2f(stXb[(btM + NN + n) * 64 + col]);
          } else if (w == 1) {
            val += pt12[n] * h2f(stXb[(btM + n) * 64 + col])
                 + pt32[n] * h2f(stXb[(btM + 2 * NN + n) * 64 + col]);
          } else {
            val += pt23[n] * h2f(stXb[(btM + NN + n) * 64 + col]);
          }
          xs1b[(btM + (long)w * NN + n) * 64 + col] = f2h(val);
        }
      }
}

// ------- t2 via MFMA: 2*(L*xs1)[mid] - stX[mid] -> fp16 ------------------
__global__ __launch_bounds__(256) void k_t2_mfma(const unsigned short* __restrict__ gsoB,
                                                 const unsigned short* __restrict__ xs1b,
                                                 const unsigned short* __restrict__ stXb,
                                                 const float* __restrict__ pt12,
                                                 const float* __restrict__ pt32,
                                                 unsigned short* __restrict__ t2b) {
  __shared__ alignas(16) unsigned short Al[128 * 40];
  __shared__ alignas(16) unsigned short Bt[64 * 40];
  int bt = blockIdx.x;
  int b = bt / TT;
  int rt_blk = blockIdx.y;
  const unsigned short* A = gsoB + (long)b * NN * GSTR;
  long vbase = (long)bt * MM + NN;
  int tid = threadIdx.x;
  int lane = tid & 63;
  int wv = __builtin_amdgcn_readfirstlane(tid >> 6);
  int lr = lane & 15, lg = lane >> 4;
  f32x4 zero4 = {0.f, 0.f, 0.f, 0.f};
  f32x4 acc[2][4];
#pragma unroll
  for (int rt = 0; rt < 2; ++rt)
#pragma unroll
    for (int c = 0; c < 4; ++c) acc[rt][c] = zero4;
  for (int kb_ = 0; kb_ < 352; kb_ += 32) {
    __syncthreads();
    for (int u = 0; u < 2; ++u) {
      int idx = tid + 256 * u;
      int row = idx >> 2, c8 = idx & 3;
      int rr = rt_blk * 128 + row; if (rr > NN - 1) rr = NN - 1;
      *(uint4*)&Al[row * 40 + c8 * 8] = *(const uint4*)&A[(long)rr * GSTR + kb_ + c8 * 8];
    }
    for (int u = 0; u < 2; ++u) {
      int idx = tid + 256 * u;
      int k = idx >> 4, c4 = idx & 15;
      int kg = kb_ + k;
#pragma unroll
      for (int j = 0; j < 4; ++j) {
        int d = c4 + 16 * j;
        unsigned short val = (kg < NN) ? xs1b[(vbase + kg) * 64 + d] : (unsigned short)0;
        Bt[d * 40 + k] = val;
      }
    }
    __syncthreads();
    half8 a0 = *(const half8*)&Al[(32 * wv + lr) * 40 + lg * 8];
    half8 a1 = *(const half8*)&Al[(32 * wv + 16 + lr) * 40 + lg * 8];
#pragma unroll
    for (int c = 0; c < 4; ++c) {
      half8 b_ = *(const half8*)&Bt[(16 * c + lr) * 40 + lg * 8];
      acc[0][c] = __builtin_amdgcn_mfma_f32_16x16x32_f16(a0, b_, acc[0][c], 0, 0, 0);
      acc[1][c] = __builtin_amdgcn_mfma_f32_16x16x32_f16(a1, b_, acc[1][c], 0, 0, 0);
    }
  }
  long btM = (long)bt * MM;
#pragma unroll
  for (int rt = 0; rt < 2; ++rt)
#pragma unroll
    for (int c = 0; c < 4; ++c)
#pragma unroll
      for (int e = 0; e < 4; ++e) {
        int n = rt_blk * 128 + 32 * wv + 16 * rt + lg * 4 + e;
        int col = 16 * c + lr;
        if (n < NN) {
          float val = 2.f * (pt12[n] * h2f(xs1b[(btM + n) * 64 + col])
                             + acc[rt][c][e]
                             + pt32[n] * h2f(xs1b[(btM + 2 * NN + n) * 64 + col]))
                      - h2f(stXb[(btM + NN + n) * 64 + col]);
          t2b[((long)bt * NN + n) * 64 + col] = f2h(val);
        }
      }
}

// ------- cheb via MFMA: [31200x192]x[192x64] + LayerNorm epilogue --------
__global__ __launch_bounds__(256) void k_cheb_mfma(const unsigned short* __restrict__ stXb,
                                                   const unsigned short* __restrict__ xs1b,
                                                   const unsigned short* __restrict__ t2b,
                                                   const float* __restrict__ cw,
                                                   const float* __restrict__ lng,
                                                   const float* __restrict__ lnb,
                                                   float* __restrict__ gcn) {
  __shared__ alignas(16) unsigned short Bt[64 * 200];  // [j][K], K=192
  __shared__ alignas(16) unsigned short Al[128 * 40];
  int tid = threadIdx.x;
  for (int u = 0; u < 48; ++u) {
    int f = tid + 256 * u;                   // f = K*64 + j
    int K = f >> 6, j = f & 63;
    Bt[j * 200 + K] = f2h(cw[f]);
  }
  int lane = tid & 63;
  int wv = __builtin_amdgcn_readfirstlane(tid >> 6);
  int lr = lane & 15, lg = lane >> 4;
  long grow0 = (long)blockIdx.x * 128;
  f32x4 zero4 = {0.f, 0.f, 0.f, 0.f};
  f32x4 acc[2][4];
#pragma unroll
  for (int rt = 0; rt < 2; ++rt)
#pragma unroll
    for (int c = 0; c < 4; ++c) acc[rt][c] = zero4;
  for (int ch = 0; ch < 6; ++ch) {
    const unsigned short* src = ch < 2 ? stXb : (ch < 4 ? xs1b : t2b);
    int koff = (ch & 1) * 32;
    __syncthreads();
    for (int u = 0; u < 2; ++u) {
      int idx = tid + 256 * u;
      int row = idx >> 2, c8 = idx & 3;
      long gr = grow0 + row; if (gr > 31199) gr = 31199;
      int bt = (int)(gr / NN), n = (int)(gr - (long)bt * NN);
      long sbase = (ch < 4) ? ((long)bt * MM + NN + n) * 64 : gr * 64;
      *(uint4*)&Al[row * 40 + c8 * 8] = *(const uint4*)&src[sbase + koff + c8 * 8];
    }
    __syncthreads();
    half8 a0 = *(const half8*)&Al[(32 * wv + lr) * 40 + lg * 8];
    half8 a1 = *(const half8*)&Al[(32 * wv + 16 + lr) * 40 + lg * 8];
#pragma unroll
    for (int c = 0; c < 4; ++c) {
      half8 b = *(const half8*)&Bt[(16 * c + lr) * 200 + ch * 32 + lg * 8];
      acc[0][c] = __builtin_amdgcn_mfma_f32_16x16x32_f16(a0, b, acc[0][c], 0, 0, 0);
      acc[1][c] = __builtin_amdgcn_mfma_f32_16x16x32_f16(a1, b, acc[1][c], 0, 0, 0);
    }
  }
  float lngv[4], lnbv[4];
#pragma unroll
  for (int c = 0; c < 4; ++c) { lngv[c] = lng[16 * c + lr]; lnbv[c] = lnb[16 * c + lr]; }
#pragma unroll
  for (int rt = 0; rt < 2; ++rt)
#pragma unroll
    for (int e = 0; e < 4; ++e) {
      float s = acc[rt][0][e] + acc[rt][1][e] + acc[rt][2][e] + acc[rt][3][e];
      for (int m = 1; m < 16; m <<= 1) s += __shfl_xor(s, m);
      float mu = s * (1.f / 64.f);
      float q = 0.f;
#pragma unroll
      for (int c = 0; c < 4; ++c) { float d = acc[rt][c][e] - mu; q += d * d; }
      for (int m = 1; m < 16; m <<= 1) q += __shfl_xor(q, m);
      float rstd = rsqrtf(q * (1.f / 64.f) + LN_EPS_);
      long gr = grow0 + 32 * wv + 16 * rt + lg * 4 + e;
      if (gr < 31200) {
#pragma unroll
        for (int c = 0; c < 4; ++c)
          gcn[gr * 64 + 16 * c + lr] = (acc[rt][c][e] - mu) * rstd * lngv[c] + lnbv[c];
      }
    }
}

// -------- mean over (t,n) per (b,d), inline scramble-gather --------------
__global__ __launch_bounds__(256) void k_mean(const unsigned short* __restrict__ semh,
                                              const float* __restrict__ gcn,
                                              float* __restrict__ mbd) {
  __shared__ float red[4][64];
  int bt = blockIdx.x;
  int b = bt / TT;
  int d = threadIdx.x & 63, g = threadIdx.x >> 6;
  float s = 0.f;
  for (int n = g; n < NN; n += 4) {
    int f = (NN + n) * 64 + d;
    int mm = f % MM, ii = f / MM;
    float a = h2f(semh[((long)bt * MM + mm) * 64 + ii]);
    float r = gcn[((long)bt * NN + n) * 64 + d];
    s += a + r;
  }
  red[g][d] = s;
  __syncthreads();
  if (threadIdx.x < 64) {
    float v = red[0][d] + red[1][d] + red[2][d] + red[3][d];
    atomicAdd(&mbd[b * 64 + d], v);
  }
}

// -------- global AFF branch ----------------------------------------------
__global__ __launch_bounds__(64) void k_glob(const float* __restrict__ mbd,
                                             const float* __restrict__ w1,
                                             const float* __restrict__ b1,
                                             const float* __restrict__ g1,
                                             const float* __restrict__ be1,
                                             const float* __restrict__ w2,
                                             const float* __restrict__ b2,
                                             const float* __restrict__ g2,
                                             const float* __restrict__ be2,
                                             float* __restrict__ xg) {
  __shared__ float ml[64];
  __shared__ float zg[16];
  int b = blockIdx.x, d = threadIdx.x;
  ml[d] = mbd[b * 64 + d] * (1.f / 3900.f);
  __syncthreads();
  float rb = rsqrtf(1.f + BN_EPS_);
  if (d < 16) {
    float a = b1[d];
    for (int i = 0; i < 64; ++i) a += w1[d * 64 + i] * ml[i];
    a = a * (g1[d] * rb) + be1[d];
    zg[d] = a > 0.f ? a : 0.f;
  }
  __syncthreads();
  float a = b2[d];
  for (int i = 0; i < 16; ++i) a += w2[d * 16 + i] * zg[i];
  xg[b * 64 + d] = a * (g2[d] * rb) + be2[d];
}

// -------- final: local AFF branch + sigmoid fuse (inline gather) ---------
__global__ __launch_bounds__(256) void k_final(const unsigned short* __restrict__ semh,
                                               const float* __restrict__ gcn,
                                               const float* __restrict__ xg,
                                               const float* __restrict__ w1,
                                               const float* __restrict__ b1,
                                               const float* __restrict__ g1,
                                               const float* __restrict__ be1,
                                               const float* __restrict__ w2,
                                               const float* __restrict__ b2,
                                               const float* __restrict__ g2,
                                               const float* __restrict__ be2,
                                               float* __restrict__ out) {
  __shared__ float w1l[16][65];
  __shared__ float w2l[64][17];
  __shared__ float xal[4][64];
  __shared__ float zll[4][16];
  int tid = threadIdx.x;
  for (int u = 0; u < 4; ++u) {
    int f = tid + 256 * u;
    w1l[f >> 6][f & 63] = w1[f];
    w2l[f >> 4][f & 15] = w2[f];
  }
  int lane = tid & 63, wv = tid >> 6;
  long row = (long)blockIdx.x * 4 + wv;        // 31,200 rows exact
  int bt = (int)(row / NN);
  int n = (int)(row - (long)bt * NN);
  int b = bt / TT;
  int f = (NN + n) * 64 + lane;
  int mm = f % MM, ii = f / MM;
  float a = h2f(semh[((long)bt * MM + mm) * 64 + ii]);
  float r = gcn[row * DD + lane];
  float xa = a + r;
  xal[wv][lane] = xa;
  __syncthreads();
  float rb = rsqrtf(1.f + BN_EPS_);
  if (lane < 16) {
    float acc = b1[lane];
#pragma unroll 8
    for (int i = 0; i < 64; ++i) acc += w1l[lane][i] * xal[wv][i];
    acc = acc * (g1[lane] * rb) + be1[lane];
    zll[wv][lane] = acc > 0.f ? acc : 0.f;
  }
  __syncthreads();
  float acc = b2[lane];
#pragma unroll
  for (int i = 0; i < 16; ++i) acc += w2l[lane][i] * zll[wv][i];
  float xl = acc * (g2[lane] * rb) + be2[lane];
  float wei = 1.f / (1.f + __expf(-(xl + xg[b * 64 + lane])));
  out[row * DD + lane] = 2.f * a * wei + 2.f * r * (1.f - wei);
}

extern "C" void kernel_launch(void* const* d_in, const int* in_sizes, int n_in,
                              void* d_out, int out_size, void* d_ws, size_t ws_size,
                              hipStream_t stream) {
  const float* x    = (const float*)d_in[0];
  const float* gso  = (const float*)d_in[1];
  const unsigned char* mask_raw = (const unsigned char*)d_in[2];
  const float* Wq   = (const float*)d_in[3];
  const float* Wk   = (const float*)d_in[4];
  const float* Wv   = (const float*)d_in[5];
  const float* chw  = (const float*)d_in[6];
  const float* pt12 = (const float*)d_in[7];
  const float* pt21 = (const float*)d_in[8];
  const float* pt23 = (const float*)d_in[9];
  const float* pt32 = (const float*)d_in[10];
  const float* lng  = (const float*)d_in[11];
  const float* lnb  = (const float*)d_in[12];
  const float* l_w1 = (const float*)d_in[13];
  const float* l_b1 = (const float*)d_in[14];
  const float* l_g1 = (const float*)d_in[15];
  const float* l_be1= (const float*)d_in[16];
  const float* l_w2 = (const float*)d_in[17];
  const float* l_b2 = (const float*)d_in[18];
  const float* l_g2 = (const float*)d_in[19];
  const float* l_be2= (const float*)d_in[20];
  const float* g_w1 = (const float*)d_in[21];
  const float* g_b1 = (const float*)d_in[22];
  const float* g_g1 = (const float*)d_in[23];
  const float* g_be1= (const float*)d_in[24];
  const float* g_w2 = (const float*)d_in[25];
  const float* g_b2 = (const float*)d_in[26];
  const float* g_g2 = (const float*)d_in[27];
  const float* g_be2= (const float*)d_in[28];

  float* base = (float*)d_ws;
  unsigned char* maskb = (unsigned char*)d_ws;
  unsigned short* gsoB = (unsigned short*)(base + WS_GSOB);
  unsigned short* stXb = (unsigned short*)(base + WS_STXB);
  unsigned short* qb   = (unsigned short*)(base + WS_QB);
  unsigned short* kb   = (unsigned short*)(base + WS_KB);
  unsigned short* vb   = (unsigned short*)(base + WS_VB);
  unsigned short* vbT  = (unsigned short*)(base + WS_VT);
  unsigned short* semh = (unsigned short*)(base + WS_SEMH);
  unsigned short* t2b  = (unsigned short*)(base + WS_T2B);

  // aliases (lifetimes disjoint):
  unsigned short* xs1b = vb;            // vb dead after k_attn
  float* gcn = (float*)qb;              // qb dead after k_attn
  float* mbd = base + WS_MBD;
  float* xg  = mbd + 512;

  k_maskprep<<<(NN * MBSTR + 255) / 256, 256, 0, stream>>>(mask_raw, maskb);
  k_gsoprep<<<3575, 256, 0, stream>>>(gso, gsoB);
  k_stx<<<23400, 256, 0, stream>>>(x, stXb);
  {
    dim3 g(732, 3);
    k_qkv_mfma<<<g, 256, 0, stream>>>(stXb, Wq, Wk, Wv, qb, kb, vb);
  }
  {
    dim3 gv(288, 3);
    k_vT<<<gv, 256, 0, stream>>>(vb, vbT);
  }
  k_attn<<<1512, 256, 0, stream>>>(qb, kb, vb, vbT, maskb, semh);
  {
    dim3 g(288, 3);
    k_xs1_mfma<<<g, 256, 0, stream>>>(gsoB, stXb, pt12, pt21, pt23, pt32, xs1b);
  }
  {
    dim3 g(96, 3);
    k_t2_mfma<<<g, 256, 0, stream>>>(gsoB, xs1b, stXb, pt12, pt32, t2b);
  }
  k_cheb_mfma<<<244, 256, 0, stream>>>(stXb, xs1b, t2b, chw, lng, lnb, gcn);
  hipMemsetAsync(mbd, 0, 1024 * sizeof(float), stream);
  k_mean<<<96, 256, 0, stream>>>(semh, gcn, mbd);
  k_glob<<<8, 64, 0, stream>>>(mbd, g_w1, g_b1, g_g1, g_be1, g_w2, g_b2, g_g2, g_be2, xg);
  k_final<<<7800, 256, 0, stream>>>(semh, gcn, xg,
                                    l_w1, l_b1, l_g1, l_be1,
                                    l_w2, l_b2, l_g2, l_be2,
                                    (float*)d_out);
}